// Round 18
// baseline (24.840 us; speedup 1.0000x reference)
//
#include <hip/hip_runtime.h>
#include <math.h>

// B=4096, O=8, E=64, I=4, V=3, P=perm(8,3)=336
// unary_feats  (B,8,64)   f32
// binary_feats (B,8,8,64) f32
// rule_unary   (4,3,64)   f32  = [12][64]
// rule_binary  (4,3,3,64) f32  = [36][64]  (rule = i*9 + n*3 + m)
// out          (B,4)      f32  (col0=sel0+sel1, col1=sel2+sel3, col2=col3=0)
//
// v18 = v11 (wave-autonomous, 2 elem/wave, grid 2048, rolling prefetch)
// with the inter-element serialization REMOVED:
//  - LDS double-buffered: per element buffer = v15's overlay layout
//    (bm 36 rows x 66 with q overlaying bm rows 0..11, + um 12x12) = 10080 B;
//    two buffers = 20160 B -> still 8 blocks/CU (160KB/20.16KB = 7.94.. -> 7?
//    No: 20160 x 8 = 161280 > 163840? 160 KiB = 163840 B; 8x20160 = 161280 <=
//    163840 ✓).
//  - No lgkmcnt guard, no sched_barrier: elem1's MFMA phase (independent,
//    prefetched) can overlap elem0's phase2/3 LDS+VALU tail at the
//    scheduler's discretion. R17 counters showed all pipes <10% busy
//    (latency-bound), so overlap of independent chains is the lever.
// Overlay safety (v15-verified): per-wave DS ops are in-order; iteration i
// reads bm rows 9i..9i+8 then writes q rows 3i..3i+2 (reads precede writes
// in program order; later iterations never re-read overwritten rows).

typedef __attribute__((ext_vector_type(8))) __bf16 bf16x8;
typedef __attribute__((ext_vector_type(4))) float  f32x4;

#define BMS 66            // bm/q row stride (floats)
#define SSU 12            // um row stride
#define BUFF (36 * BMS + 12 * SSU)   // 2520 floats = 10080 B per element buffer

__device__ inline bf16x8 cvt2(const float4 v0, const float4 v1) {
    bf16x8 r;
    r[0] = (__bf16)v0.x; r[1] = (__bf16)v0.y; r[2] = (__bf16)v0.z; r[3] = (__bf16)v0.w;
    r[4] = (__bf16)v1.x; r[5] = (__bf16)v1.y; r[6] = (__bf16)v1.z; r[7] = (__bf16)v1.w;
    return r;
}

__global__ __launch_bounds__(64, 2) void rule_learner_kernel(
    const float* __restrict__ uf,    // (B,8,64)
    const float* __restrict__ bfe,   // (B,8,8,64)
    const float* __restrict__ ru,    // [12][64]
    const float* __restrict__ rb,    // [36][64]
    float* __restrict__ out)         // (B,4)
{
    const int b0    = blockIdx.x * 2;
    const int lane  = threadIdx.x;   // one wave per block
    const int row16 = lane & 15;
    const int kg    = lane >> 4;
    const int kb    = kg * 8;

    __shared__ float smem[2 * BUFF];   // 20160 B (double-buffered)

    // ---- elem0 feature loads (only exposed-latency loads) ----
    float4 af[4][4], uA[4];
    {
        const float* base = bfe + (size_t)b0 * 4096;
        #pragma unroll
        for (int t = 0; t < 4; ++t) {
            const float* rp = base + (size_t)(t * 16 + row16) * 64 + kb;
            af[t][0] = *(const float4*)rp;
            af[t][1] = *(const float4*)(rp + 4);
            af[t][2] = *(const float4*)(rp + 32);
            af[t][3] = *(const float4*)(rp + 36);
        }
        const float* up = uf + (size_t)b0 * 512 + (row16 < 8 ? row16 : 7) * 64 + kb;
        uA[0] = *(const float4*)up;        uA[1] = *(const float4*)(up + 4);
        uA[2] = *(const float4*)(up + 32); uA[3] = *(const float4*)(up + 36);
    }

    // ---- rule fragments packed in-wave once (L1-hot f32; clamp padding) ----
    bf16x8 rbf[6], ruf0, ruf1;
    {
        #pragma unroll
        for (int nt = 0; nt < 3; ++nt) {
            const int rule = nt * 16 + row16;
            const float* rp = rb + (rule < 36 ? rule : 35) * 64 + kb;
            rbf[nt * 2 + 0] = cvt2(*(const float4*)rp,        *(const float4*)(rp + 4));
            rbf[nt * 2 + 1] = cvt2(*(const float4*)(rp + 32), *(const float4*)(rp + 36));
        }
        const float* up = ru + (row16 < 12 ? row16 : 11) * 64 + kb;
        ruf0 = cvt2(*(const float4*)up,        *(const float4*)(up + 4));
        ruf1 = cvt2(*(const float4*)(up + 32), *(const float4*)(up + 36));
    }

    #pragma unroll
    for (int e = 0; e < 2; ++e) {
        float* bm = smem + e * BUFF;        // [rule][pos], stride 66
        float* qq = bm;                     // q rows 0..11 overlay bm rows 0..11
        float* um = bm + 36 * BMS;          // [i*3+n][v], stride 12

        // ---- phase 1: MFMA matches into bm/um (consumes af/uA) ----
        #pragma unroll
        for (int t = 0; t < 4; ++t) {
            const bf16x8 a0 = cvt2(af[t][0], af[t][1]);
            const bf16x8 a1 = cvt2(af[t][2], af[t][3]);
            #pragma unroll
            for (int nt = 0; nt < 3; ++nt) {
                f32x4 acc = {0.f, 0.f, 0.f, 0.f};
                acc = __builtin_amdgcn_mfma_f32_16x16x32_bf16(a0, rbf[nt * 2 + 0], acc, 0, 0, 0);
                acc = __builtin_amdgcn_mfma_f32_16x16x32_bf16(a1, rbf[nt * 2 + 1], acc, 0, 0, 0);
                const int rule = nt * 16 + row16;
                if (rule < 36)
                    *(float4*)&bm[rule * BMS + t * 16 + kg * 4] = *(float4*)&acc;
            }
        }
        {
            const bf16x8 ua0 = cvt2(uA[0], uA[1]);
            const bf16x8 ua1 = cvt2(uA[2], uA[3]);
            f32x4 acc = {0.f, 0.f, 0.f, 0.f};
            acc = __builtin_amdgcn_mfma_f32_16x16x32_bf16(ua0, ruf0, acc, 0, 0, 0);
            acc = __builtin_amdgcn_mfma_f32_16x16x32_bf16(ua1, ruf1, acc, 0, 0, 0);
            if (row16 < 12 && kg < 2)
                *(float4*)&um[row16 * SSU + kg * 4] = *(float4*)&acc;
        }

        // ---- issue elem1 loads (af/uA free again; hides under phases 2-3) ----
        if (e == 0) {
            const float* base = bfe + (size_t)(b0 + 1) * 4096;
            #pragma unroll
            for (int t = 0; t < 4; ++t) {
                const float* rp = base + (size_t)(t * 16 + row16) * 64 + kb;
                af[t][0] = *(const float4*)rp;
                af[t][1] = *(const float4*)(rp + 4);
                af[t][2] = *(const float4*)(rp + 32);
                af[t][3] = *(const float4*)(rp + 36);
            }
            const float* up = uf + (size_t)(b0 + 1) * 512
                            + (row16 < 8 ? row16 : 7) * 64 + kb;
            uA[0] = *(const float4*)up;        uA[1] = *(const float4*)(up + 4);
            uA[2] = *(const float4*)(up + 32); uA[3] = *(const float4*)(up + 36);
        }

        // ---- phase 2: q-tables (lane = pair (x,y)); q overlays bm 0..11 ----
        {
            const int x = lane >> 3;
            const int y = lane & 7;
            #pragma unroll
            for (int i = 0; i < 4; ++i) {
                const float* bmi = bm + i * 9 * BMS;
                const float* umi = um + i * 3 * SSU;
                const float q01 = umi[x] + umi[SSU + y]
                                + bmi[0 * BMS + x * 9] + bmi[4 * BMS + y * 9]
                                + bmi[1 * BMS + x * 8 + y] + bmi[3 * BMS + y * 8 + x];
                const float q02 = umi[2 * SSU + y] + bmi[8 * BMS + y * 9]
                                + bmi[2 * BMS + x * 8 + y] + bmi[6 * BMS + y * 8 + x];
                const float q12 = bmi[5 * BMS + x * 8 + y] + bmi[7 * BMS + y * 8 + x];
                qq[(i * 3 + 0) * BMS + lane] = q01;
                qq[(i * 3 + 1) * BMS + lane] = q02;
                qq[(i * 3 + 2) * BMS + lane] = q12;
            }
        }

        // ---- phase 3: lane = ordered pair (a,bb), sweep cc for all 4 i ----
        float mn[4] = {INFINITY, INFINITY, INFINITY, INFINITY};
        if (lane < 56) {
            const int a  = lane / 7;
            const int o  = lane - a * 7;
            const int bb = o + (o >= a);
            #pragma unroll
            for (int i = 0; i < 4; ++i) {
                const float bs  = qq[(i * 3 + 0) * BMS + a * 8 + bb];
                const float4 c0 = *(const float4*)&qq[(i * 3 + 1) * BMS + a * 8];
                const float4 c1 = *(const float4*)&qq[(i * 3 + 1) * BMS + a * 8 + 4];
                const float4 d0 = *(const float4*)&qq[(i * 3 + 2) * BMS + bb * 8];
                const float4 d1 = *(const float4*)&qq[(i * 3 + 2) * BMS + bb * 8 + 4];
                float vv[8];
                vv[0] = c0.x + d0.x; vv[1] = c0.y + d0.y;
                vv[2] = c0.z + d0.z; vv[3] = c0.w + d0.w;
                vv[4] = c1.x + d1.x; vv[5] = c1.y + d1.y;
                vv[6] = c1.z + d1.z; vv[7] = c1.w + d1.w;
                float m = INFINITY;
                #pragma unroll
                for (int cc = 0; cc < 8; ++cc) {
                    const float s = (cc == a || cc == bb) ? INFINITY : (bs + vv[cc]);
                    m = fminf(m, s);
                }
                mn[i] = m;
            }
        }
        #pragma unroll
        for (int s = 1; s <= 32; s <<= 1) {
            #pragma unroll
            for (int i = 0; i < 4; ++i) mn[i] = fminf(mn[i], __shfl_xor(mn[i], s));
        }
        if (lane == 0) {
            const float mx = fmaxf(fmaxf(mn[0], mn[1]), fmaxf(mn[2], mn[3]));
            const float e0 = expf(mn[0] - mx), e1 = expf(mn[1] - mx);
            const float e2 = expf(mn[2] - mx), e3 = expf(mn[3] - mx);
            const float inv = 1.f / (e0 + e1 + e2 + e3);
            *(float4*)(out + (size_t)(b0 + e) * 4) =
                make_float4((e0 + e1) * inv, (e2 + e3) * inv, 0.f, 0.f);
        }
        // no guard, no sched_barrier: next element uses the OTHER LDS buffer;
        // its MFMA chain is independent and may overlap this tail.
    }
}

extern "C" void kernel_launch(void* const* d_in, const int* in_sizes, int n_in,
                              void* d_out, int out_size, void* d_ws, size_t ws_size,
                              hipStream_t stream) {
    const float* uf = (const float*)d_in[0];   // (4096,8,64)
    const float* bf = (const float*)d_in[1];   // (4096,8,8,64)
    const float* ru = (const float*)d_in[2];   // (4,3,64)
    const float* rb = (const float*)d_in[3];   // (4,3,3,64)
    float* out = (float*)d_out;                // (4096,4)

    const int B = in_sizes[0] / (8 * 64);      // 4096
    rule_learner_kernel<<<B / 2, 64, 0, stream>>>(uf, bf, ru, rb, out);
}

// Round 19
// 20.010 us; speedup vs baseline: 1.2414x; 1.2414x over previous
//
#include <hip/hip_runtime.h>
#include <math.h>

// B=4096, O=8, E=64, I=4, V=3, P=perm(8,3)=336
// unary_feats  (B,8,64)   f32
// binary_feats (B,8,8,64) f32
// rule_unary   (4,3,64)   f32  = [12][64]
// rule_binary  (4,3,3,64) f32  = [36][64]  (rule = i*9 + n*3 + m)
// out          (B,4)      f32  (col0=sel0+sel1, col1=sel2+sel3, col2=col3=0)
//
// v19 = v11 (wave-autonomous, 2 elem/wave, zero barriers, single dispatch,
// rolling prefetch) + WAVE STAGGER: R17 counters showed 10% occupancy with
// all pipes <10% busy -> waves phase-locked (identical code, simultaneous
// start): all 2048 waves issue their 18KB load burst at t=0 (37MB demand),
// queueing inflates latency, and co-resident waves stall & compute in
// lockstep (no mutual hiding). Fix: stagger residency layers
// (blockIdx>>8 = layer 0..7) by ~layer*576cy via s_sleep so load bursts
// tile the memory stream and compute slots interleave across waves.

typedef __attribute__((ext_vector_type(8))) __bf16 bf16x8;
typedef __attribute__((ext_vector_type(4))) float  f32x4;

#define BMS 68
#define QS3 68

__device__ inline bf16x8 cvt2(const float4 v0, const float4 v1) {
    bf16x8 r;
    r[0] = (__bf16)v0.x; r[1] = (__bf16)v0.y; r[2] = (__bf16)v0.z; r[3] = (__bf16)v0.w;
    r[4] = (__bf16)v1.x; r[5] = (__bf16)v1.y; r[6] = (__bf16)v1.z; r[7] = (__bf16)v1.w;
    return r;
}

__global__ __launch_bounds__(64, 2) void rule_learner_kernel(
    const float* __restrict__ uf,    // (B,8,64)
    const float* __restrict__ bfe,   // (B,8,8,64)
    const float* __restrict__ ru,    // [12][64]
    const float* __restrict__ rb,    // [36][64]
    float* __restrict__ out)         // (B,4)
{
    // ---- wave stagger: desync residency layers before the load burst ----
    {
        const int layer = (blockIdx.x >> 8) & 7;
        for (int s = 0; s < layer; ++s) __builtin_amdgcn_s_sleep(9);  // ~576cy each
    }

    const int b0    = blockIdx.x * 2;
    const int lane  = threadIdx.x;   // one wave per block
    const int row16 = lane & 15;
    const int kg    = lane >> 4;
    const int kb    = kg * 8;

    __shared__ float bm[36 * BMS];   // 9792 B  [rule][pos]
    __shared__ float um[12 * 12];    // 576 B   [i*3+n][v]
    __shared__ float q [12 * QS3];   // 3264 B  [i*3+t][pair]

    // ---- elem0 feature loads (issue first: coldest) ----
    float4 af[4][4], uA[4];
    {
        const float* base = bfe + (size_t)b0 * 4096;
        #pragma unroll
        for (int t = 0; t < 4; ++t) {
            const float* rp = base + (size_t)(t * 16 + row16) * 64 + kb;
            af[t][0] = *(const float4*)rp;
            af[t][1] = *(const float4*)(rp + 4);
            af[t][2] = *(const float4*)(rp + 32);
            af[t][3] = *(const float4*)(rp + 36);
        }
        const float* up = uf + (size_t)b0 * 512 + (row16 < 8 ? row16 : 7) * 64 + kb;
        uA[0] = *(const float4*)up;        uA[1] = *(const float4*)(up + 4);
        uA[2] = *(const float4*)(up + 32); uA[3] = *(const float4*)(up + 36);
    }

    // ---- rule fragments packed in-wave (L1-hot f32; clamp padding) ----
    bf16x8 rbf[6], ruf0, ruf1;
    {
        #pragma unroll
        for (int nt = 0; nt < 3; ++nt) {
            const int rule = nt * 16 + row16;
            const float* rp = rb + (rule < 36 ? rule : 35) * 64 + kb;
            rbf[nt * 2 + 0] = cvt2(*(const float4*)rp,        *(const float4*)(rp + 4));
            rbf[nt * 2 + 1] = cvt2(*(const float4*)(rp + 32), *(const float4*)(rp + 36));
        }
        const float* up = ru + (row16 < 12 ? row16 : 11) * 64 + kb;
        ruf0 = cvt2(*(const float4*)up,        *(const float4*)(up + 4));
        ruf1 = cvt2(*(const float4*)(up + 32), *(const float4*)(up + 36));
    }

    #pragma unroll
    for (int e = 0; e < 2; ++e) {
        // ---- phase 1: MFMA matches into bm/um ----
        #pragma unroll
        for (int t = 0; t < 4; ++t) {
            const bf16x8 a0 = cvt2(af[t][0], af[t][1]);
            const bf16x8 a1 = cvt2(af[t][2], af[t][3]);
            #pragma unroll
            for (int nt = 0; nt < 3; ++nt) {
                f32x4 acc = {0.f, 0.f, 0.f, 0.f};
                acc = __builtin_amdgcn_mfma_f32_16x16x32_bf16(a0, rbf[nt * 2 + 0], acc, 0, 0, 0);
                acc = __builtin_amdgcn_mfma_f32_16x16x32_bf16(a1, rbf[nt * 2 + 1], acc, 0, 0, 0);
                const int rule = nt * 16 + row16;
                if (rule < 36)
                    *(float4*)&bm[rule * BMS + t * 16 + kg * 4] = *(float4*)&acc;
            }
        }
        {
            const bf16x8 ua0 = cvt2(uA[0], uA[1]);
            const bf16x8 ua1 = cvt2(uA[2], uA[3]);
            f32x4 acc = {0.f, 0.f, 0.f, 0.f};
            acc = __builtin_amdgcn_mfma_f32_16x16x32_bf16(ua0, ruf0, acc, 0, 0, 0);
            acc = __builtin_amdgcn_mfma_f32_16x16x32_bf16(ua1, ruf1, acc, 0, 0, 0);
            if (row16 < 12 && kg < 2)
                *(float4*)&um[row16 * 12 + kg * 4] = *(float4*)&acc;
        }

        // ---- issue elem1 loads NOW (latency hides under phases 2-3) ----
        if (e == 0) {
            const float* base = bfe + (size_t)(b0 + 1) * 4096;
            #pragma unroll
            for (int t = 0; t < 4; ++t) {
                const float* rp = base + (size_t)(t * 16 + row16) * 64 + kb;
                af[t][0] = *(const float4*)rp;
                af[t][1] = *(const float4*)(rp + 4);
                af[t][2] = *(const float4*)(rp + 32);
                af[t][3] = *(const float4*)(rp + 36);
            }
            const float* up = uf + (size_t)(b0 + 1) * 512
                            + (row16 < 8 ? row16 : 7) * 64 + kb;
            uA[0] = *(const float4*)up;        uA[1] = *(const float4*)(up + 4);
            uA[2] = *(const float4*)(up + 32); uA[3] = *(const float4*)(up + 36);
        }

        // ---- phase 2: q-tables for all 4 rule-sets (lane = pair (x,y)) ----
        {
            const int x = lane >> 3;
            const int y = lane & 7;
            #pragma unroll
            for (int i = 0; i < 4; ++i) {
                const float* bmi = bm + i * 9 * BMS;
                const float* umi = um + i * 3 * 12;
                const float q01 = umi[x] + umi[12 + y]
                                + bmi[0 * BMS + x * 9] + bmi[4 * BMS + y * 9]
                                + bmi[1 * BMS + x * 8 + y] + bmi[3 * BMS + y * 8 + x];
                const float q02 = umi[24 + y] + bmi[8 * BMS + y * 9]
                                + bmi[2 * BMS + x * 8 + y] + bmi[6 * BMS + y * 8 + x];
                const float q12 = bmi[5 * BMS + x * 8 + y] + bmi[7 * BMS + y * 8 + x];
                q[(i * 3 + 0) * QS3 + lane] = q01;
                q[(i * 3 + 1) * QS3 + lane] = q02;
                q[(i * 3 + 2) * QS3 + lane] = q12;
            }
        }

        // ---- phase 3: lane = ordered pair (a,bb), sweep cc for all 4 i ----
        float mn[4] = {INFINITY, INFINITY, INFINITY, INFINITY};
        if (lane < 56) {
            const int a  = lane / 7;
            const int o  = lane - a * 7;
            const int bb = o + (o >= a);
            #pragma unroll
            for (int i = 0; i < 4; ++i) {
                const float bs  = q[(i * 3 + 0) * QS3 + a * 8 + bb];
                const float4 c0 = *(const float4*)&q[(i * 3 + 1) * QS3 + a * 8];
                const float4 c1 = *(const float4*)&q[(i * 3 + 1) * QS3 + a * 8 + 4];
                const float4 d0 = *(const float4*)&q[(i * 3 + 2) * QS3 + bb * 8];
                const float4 d1 = *(const float4*)&q[(i * 3 + 2) * QS3 + bb * 8 + 4];
                float vv[8];
                vv[0] = c0.x + d0.x; vv[1] = c0.y + d0.y;
                vv[2] = c0.z + d0.z; vv[3] = c0.w + d0.w;
                vv[4] = c1.x + d1.x; vv[5] = c1.y + d1.y;
                vv[6] = c1.z + d1.z; vv[7] = c1.w + d1.w;
                float m = INFINITY;
                #pragma unroll
                for (int cc = 0; cc < 8; ++cc) {
                    const float s = (cc == a || cc == bb) ? INFINITY : (bs + vv[cc]);
                    m = fminf(m, s);
                }
                mn[i] = m;
            }
        }
        #pragma unroll
        for (int s = 1; s <= 32; s <<= 1) {
            #pragma unroll
            for (int i = 0; i < 4; ++i) mn[i] = fminf(mn[i], __shfl_xor(mn[i], s));
        }
        if (lane == 0) {
            const float mx = fmaxf(fmaxf(mn[0], mn[1]), fmaxf(mn[2], mn[3]));
            const float e0 = expf(mn[0] - mx), e1 = expf(mn[1] - mx);
            const float e2 = expf(mn[2] - mx), e3 = expf(mn[3] - mx);
            const float inv = 1.f / (e0 + e1 + e2 + e3);
            *(float4*)(out + (size_t)(b0 + e) * 4) =
                make_float4((e0 + e1) * inv, (e2 + e3) * inv, 0.f, 0.f);
        }

        // ---- LDS reuse guard between elements (WAR): DS-only wait keeps the
        // elem1 global prefetch in flight; sched_barrier blocks hoisting. ----
        if (e == 0) {
            asm volatile("s_waitcnt lgkmcnt(0)" ::: "memory");
            __builtin_amdgcn_sched_barrier(0);
        }
    }
}

extern "C" void kernel_launch(void* const* d_in, const int* in_sizes, int n_in,
                              void* d_out, int out_size, void* d_ws, size_t ws_size,
                              hipStream_t stream) {
    const float* uf = (const float*)d_in[0];   // (4096,8,64)
    const float* bf = (const float*)d_in[1];   // (4096,8,8,64)
    const float* ru = (const float*)d_in[2];   // (4,3,64)
    const float* rb = (const float*)d_in[3];   // (4,3,3,64)
    float* out = (float*)d_out;                // (4096,4)

    const int B = in_sizes[0] / (8 * 64);      // 4096
    rule_learner_kernel<<<B / 2, 64, 0, stream>>>(uf, bf, ru, rb, out);
}